// Round 10
// baseline (54.579 us; speedup 1.0000x reference)
//
#include <hip/hip_runtime.h>
#include <hip/hip_cooperative_groups.h>
namespace cg = cooperative_groups;

#define NBLK 256
// float offsets into ws
#define WS_MP   0        // mpart 4*256
#define WS_LP   1024     // lpart 4*256
#define WS_YV   2048     // yv 1024
#define WS_B2   3072     // bias2 256
#define WS_M2   3328     // M2 256*1024
#define WS_YP   265472   // ypart 256*1024
#define WS_CNT  527616   // counters (ints)

__device__ __forceinline__ float dot4(float4 a, float4 b) {
  return a.x * b.x + a.y * b.y + a.z * b.z + a.w * b.w;
}

// ---- sync: release-add signal; acquire-LOAD poll (no RMW storm — R9 lesson) ----
__device__ __forceinline__ void sig_rel(int* p) {
  __threadfence();
  __syncthreads();
  if (threadIdx.x == 0) atomicAdd(p, 1);
}
__device__ __forceinline__ void spin_acq(int* p, int target) {
  if (threadIdx.x == 0) {
    while (__hip_atomic_load(p, __ATOMIC_ACQUIRE, __HIP_MEMORY_SCOPE_AGENT) < target)
      __builtin_amdgcn_s_sleep(8);
  }
  __syncthreads();
  __threadfence();
}

// ---- redundant q/kq/c4 per block (reads Wq+Wk from L2; kills the A->B sync) ----
__device__ __forceinline__ void make_kq(const float* __restrict__ x, const float* __restrict__ W,
                                        const float* __restrict__ inb,
                                        float* xs, float* qls, float* kqls, float* c4ls,
                                        float* red2, int t) {
  const int lane = t & 63, w = t >> 6;
  if (t < 256) xs[t] = x[t];
  __syncthreads();
  const float4 xv0 = *(const float4*)&xs[lane * 4];
  // q: wave w computes rows w*32..w*32+31, batches of 4 for ILP
  for (int k = 0; k < 32; k += 4) {
    float p[4];
#pragma unroll
    for (int j = 0; j < 4; ++j) {
      const int row = w * 32 + k + j;
      float4 wv = *(const float4*)&W[(size_t)row * 256 + lane * 4];
      p[j] = dot4(wv, xv0);
    }
#pragma unroll
    for (int m = 1; m < 64; m <<= 1) {
#pragma unroll
      for (int j = 0; j < 4; ++j) p[j] += __shfl_xor(p[j], m);
    }
    if (lane == 0) {
#pragma unroll
      for (int j = 0; j < 4; ++j) qls[w * 32 + k + j] = p[j] + inb[w * 32 + k + j];
    }
  }
  __syncthreads();
  // kq[h][c] = sum_d Wk[h*64+d][c]*q[h*64+d]; thread owns c=t&255, g=t>>8 splits d
  const int c = t & 255, g = t >> 8;
  float acc0 = 0.f, acc1 = 0.f, acc2 = 0.f, acc3 = 0.f;
#pragma unroll 4
  for (int dd = 0; dd < 32; ++dd) {
    const int d = g * 32 + dd;
    acc0 += W[(size_t)(256 + 0 * 64 + d) * 256 + c] * qls[0 * 64 + d];
    acc1 += W[(size_t)(256 + 1 * 64 + d) * 256 + c] * qls[1 * 64 + d];
    acc2 += W[(size_t)(256 + 2 * 64 + d) * 256 + c] * qls[2 * 64 + d];
    acc3 += W[(size_t)(256 + 3 * 64 + d) * 256 + c] * qls[3 * 64 + d];
  }
  red2[g * 1024 + 0 * 256 + c] = acc0;
  red2[g * 1024 + 1 * 256 + c] = acc1;
  red2[g * 1024 + 2 * 256 + c] = acc2;
  red2[g * 1024 + 3 * 256 + c] = acc3;
  __syncthreads();
  if (g == 0) {
#pragma unroll
    for (int h = 0; h < 4; ++h)
      kqls[h * 256 + c] = red2[h * 256 + c] + red2[1024 + h * 256 + c];
  } else {
    const int hh = w - 4;
    float v = qls[hh * 64 + lane] * inb[256 + hh * 64 + lane];
#pragma unroll
    for (int m = 1; m < 64; m <<= 1) v += __shfl_xor(v, m);
    if (lane == 0) c4ls[hh] = v;
  }
  __syncthreads();
}

// ---- M2 tile (b2 in 0..127): M2[e][h*256+c] = sum_d Wout[e][h*64+d]*Wv[h*64+d][c] ----
__device__ __forceinline__ void phaseA_m2(const float* __restrict__ W, const float* __restrict__ Wout,
                                          float* __restrict__ M2, float* sh, int b2, int t) {
  float* wout_t = sh;  // [8][64]
  const int tile = b2 >> 1, sub = b2 & 1;
  const int h = tile >> 4, e0 = (tile & 15) * 16 + sub * 8;
  {
    const int e = t >> 6, d = t & 63;
    wout_t[e * 64 + d] = Wout[(size_t)(e0 + e) * 256 + h * 64 + d];
  }
  __syncthreads();
  const int c = t & 255, eh = t >> 8;
  float acc[4] = {0.f, 0.f, 0.f, 0.f};
#pragma unroll 8
  for (int d = 0; d < 64; ++d) {
    const float wv = W[(size_t)(512 + h * 64 + d) * 256 + c];
#pragma unroll
    for (int e = 0; e < 4; ++e) acc[e] += wv * wout_t[(eh * 4 + e) * 64 + d];
  }
#pragma unroll
  for (int e = 0; e < 4; ++e)
    M2[(size_t)(e0 + eh * 4 + e) * 1024 + h * 256 + c] = acc[e];
}

// ---- bias2[e] = Wout[e].bv + bout[e]; b in 0..15 ----
__device__ __forceinline__ void phaseA_b2(const float* __restrict__ Wout, const float* __restrict__ inb,
                                          const float* __restrict__ bout, float* __restrict__ bias2,
                                          float* sh, int b, int t) {
  float* red = sh;  // 512
  const int og = t >> 5, seg = t & 31;
  const int e = b * 16 + og;
  float acc = 0.f;
#pragma unroll
  for (int j = 0; j < 8; ++j)
    acc += Wout[(size_t)e * 256 + seg * 8 + j] * inb[512 + seg * 8 + j];
  red[og * 32 + seg] = acc;
  __syncthreads();
  if (t < 16) {
    float s = bout[b * 16 + t];
#pragma unroll
    for (int i = 0; i < 32; ++i) s += red[t * 32 + i];
    bias2[b * 16 + t] = s;
  }
}

// ---- Phase B (verified R8/R9 core; kq/c4 now from LDS) ----
__device__ __forceinline__ float bscore(float4 xv, float4 kq0, float4 kq1, float4 kq2,
                                        float4 kq3, float c4v, int lane) {
  float p0 = dot4(xv, kq0), p1 = dot4(xv, kq1), p2 = dot4(xv, kq2), p3 = dot4(xv, kq3);
  const bool b1 = (lane & 2) != 0;
  float keep0 = b1 ? p2 : p0, send0 = b1 ? p0 : p2;
  keep0 += __shfl_xor(send0, 2);
  float keep1 = b1 ? p3 : p1, send1 = b1 ? p1 : p3;
  keep1 += __shfl_xor(send1, 2);
  const bool b0 = (lane & 1) != 0;
  float vv = b0 ? keep1 : keep0, sv = b0 ? keep0 : keep1;
  vv += __shfl_xor(sv, 1);
  vv += __shfl_xor(vv, 4);
  vv += __shfl_xor(vv, 8);
  vv += __shfl_xor(vv, 16);
  vv += __shfl_xor(vv, 32);
  return (vv + c4v) * 0.125f;
}

__device__ __forceinline__ void phaseB_core(const float4* xvA, const float4* xvB,
                                            const float* kq, const float* c4,
                                            float* __restrict__ ypart, float* __restrict__ mpart,
                                            float* __restrict__ lpart, float* yls, int bid, int t) {
  float* sml = yls + 8192;  // 32
  float* sll = yls + 8224;  // 32
  const int lane = t & 63, w = t >> 6;
  const int hme = lane & 3;
  const float4 kq0 = *(const float4*)&kq[0 * 256 + lane * 4];
  const float4 kq1 = *(const float4*)&kq[1 * 256 + lane * 4];
  const float4 kq2 = *(const float4*)&kq[2 * 256 + lane * 4];
  const float4 kq3 = *(const float4*)&kq[3 * 256 + lane * 4];
  const float c4v = c4[hme];

  float vA[8];
#pragma unroll
  for (int r = 0; r < 8; ++r) vA[r] = bscore(xvA[r], kq0, kq1, kq2, kq3, c4v, lane);
  float m = vA[0];
#pragma unroll
  for (int r = 1; r < 8; ++r) m = fmaxf(m, vA[r]);

  float l = 0.f;
  float4 a[4];
#pragma unroll
  for (int k = 0; k < 4; ++k) a[k] = (float4){0.f, 0.f, 0.f, 0.f};
#pragma unroll
  for (int r = 0; r < 8; ++r) {
    const float e0 = __expf(vA[r] - m);
    l += e0;
    const float e1 = __shfl_xor(e0, 1);
    const float e2 = __shfl_xor(e0, 2);
    const float e3 = __shfl_xor(e0, 3);
    a[0].x += e0 * xvA[r].x; a[0].y += e0 * xvA[r].y; a[0].z += e0 * xvA[r].z; a[0].w += e0 * xvA[r].w;
    a[1].x += e1 * xvA[r].x; a[1].y += e1 * xvA[r].y; a[1].z += e1 * xvA[r].z; a[1].w += e1 * xvA[r].w;
    a[2].x += e2 * xvA[r].x; a[2].y += e2 * xvA[r].y; a[2].z += e2 * xvA[r].z; a[2].w += e2 * xvA[r].w;
    a[3].x += e3 * xvA[r].x; a[3].y += e3 * xvA[r].y; a[3].z += e3 * xvA[r].z; a[3].w += e3 * xvA[r].w;
  }

  float vB[8];
#pragma unroll
  for (int r = 0; r < 8; ++r) vB[r] = bscore(xvB[r], kq0, kq1, kq2, kq3, c4v, lane);
  float mB = vB[0];
#pragma unroll
  for (int r = 1; r < 8; ++r) mB = fmaxf(mB, vB[r]);

  {  // online merge with per-head rescale factors (verified R8)
    const float mN = fmaxf(m, mB);
    const float fown = __expf(m - mN);
    l *= fown;
    const float f1 = __shfl_xor(fown, 1);
    const float f2 = __shfl_xor(fown, 2);
    const float f3 = __shfl_xor(fown, 3);
    a[0].x *= fown; a[0].y *= fown; a[0].z *= fown; a[0].w *= fown;
    a[1].x *= f1;   a[1].y *= f1;   a[1].z *= f1;   a[1].w *= f1;
    a[2].x *= f2;   a[2].y *= f2;   a[2].z *= f2;   a[2].w *= f2;
    a[3].x *= f3;   a[3].y *= f3;   a[3].z *= f3;   a[3].w *= f3;
    m = mN;
  }
#pragma unroll
  for (int r = 0; r < 8; ++r) {
    const float e0 = __expf(vB[r] - m);
    l += e0;
    const float e1 = __shfl_xor(e0, 1);
    const float e2 = __shfl_xor(e0, 2);
    const float e3 = __shfl_xor(e0, 3);
    a[0].x += e0 * xvB[r].x; a[0].y += e0 * xvB[r].y; a[0].z += e0 * xvB[r].z; a[0].w += e0 * xvB[r].w;
    a[1].x += e1 * xvB[r].x; a[1].y += e1 * xvB[r].y; a[1].z += e1 * xvB[r].z; a[1].w += e1 * xvB[r].w;
    a[2].x += e2 * xvB[r].x; a[2].y += e2 * xvB[r].y; a[2].z += e2 * xvB[r].z; a[2].w += e2 * xvB[r].w;
    a[3].x += e3 * xvB[r].x; a[3].y += e3 * xvB[r].y; a[3].z += e3 * xvB[r].z; a[3].w += e3 * xvB[r].w;
  }

  __syncthreads();
  if (lane < 4) { sml[w * 4 + lane] = m; sll[w * 4 + lane] = l; }
  __syncthreads();

#pragma unroll
  for (int k = 0; k < 4; ++k) {
    const int h = hme ^ k;
    float mb = sml[h];
#pragma unroll
    for (int i = 1; i < 8; ++i) mb = fmaxf(mb, sml[i * 4 + h]);
    const float f = __expf(sml[w * 4 + h] - mb);
    float4 av;
    av.x = a[k].x * f; av.y = a[k].y * f; av.z = a[k].z * f; av.w = a[k].w * f;
    *(float4*)&yls[w * 1024 + h * 256 + lane * 4] = av;
  }
  __syncthreads();

  if (t < 4) {
    float mb = sml[t];
#pragma unroll
    for (int i = 1; i < 8; ++i) mb = fmaxf(mb, sml[i * 4 + t]);
    float lb = 0.f;
#pragma unroll
    for (int i = 0; i < 8; ++i) lb += sll[i * 4 + t] * __expf(sml[i * 4 + t] - mb);
    mpart[t * NBLK + bid] = mb;
    lpart[t * NBLK + bid] = lb;
  }
  float* yp = &ypart[(size_t)bid * 1024];
#pragma unroll
  for (int o = t; o < 1024; o += 512) {
    float s = 0.f;
#pragma unroll
    for (int i = 0; i < 8; ++i) s += yls[i * 1024 + o];
    yp[o] = s;
  }
}

// ---- Phase C (verbatim-verified): 64 blocks, 16 outputs each ----
__device__ __forceinline__ void phaseC(const float* __restrict__ ypart, const float* __restrict__ mpart,
                                       const float* __restrict__ lpart, float* __restrict__ yv,
                                       float* sh, int bid, int t) {
  float* mred = sh;           // 256
  float* scales = sh + 256;   // 256
  float* lred = sh + 512;     // 256
  float* sred = sh + 768;     // 512
  const int h = bid >> 4;
  const int o0 = bid * 16;
  if (t < 256) mred[t] = mpart[h * 256 + t];
  __syncthreads();
  for (int s = 128; s > 0; s >>= 1) {
    if (t < s) mred[t] = fmaxf(mred[t], mred[t + s]);
    __syncthreads();
  }
  const float mg = mred[0];
  if (t < 256) {
    const float sc = __expf(mpart[h * 256 + t] - mg);
    scales[t] = sc;
    lred[t] = lpart[h * 256 + t] * sc;
  }
  __syncthreads();
  for (int s = 128; s > 0; s >>= 1) {
    if (t < s) lred[t] += lred[t + s];
    __syncthreads();
  }
  const float inv = 1.0f / lred[0];
  const int ol = t & 15, bg = t >> 4;
  float s = 0.f;
#pragma unroll
  for (int j = 0; j < 8; ++j) {
    const int b = bg * 8 + j;
    s += ypart[(size_t)b * 1024 + o0 + ol] * scales[b];
  }
  sred[bg * 16 + ol] = s;
  __syncthreads();
  if (t < 16) {
    float tot = 0.f;
#pragma unroll
    for (int g = 0; g < 32; ++g) tot += sred[g * 16 + t];
    yv[o0 + t] = tot * inv;
  }
}

// ---- Phase D4: 64 blocks, 4 outputs each; reads full yv + M2 slice ----
__device__ __forceinline__ void phaseD4(const float* __restrict__ M2, const float* __restrict__ yv,
                                        const float* __restrict__ bias2, float* __restrict__ out,
                                        float* sh, int bid, int t) {
  float* yls2 = sh;          // 1024
  float* smo = sh + 1024;    // 8
  const int lane = t & 63, w = t >> 6;
  for (int i = t; i < 1024; i += 512) yls2[i] = yv[i];
  __syncthreads();
  const int eidx = t >> 7, seg = t & 127;
  const int e = bid * 4 + eidx;
  const float4* m4 = (const float4*)&M2[(size_t)e * 1024];
  const float4* y4 = (const float4*)yls2;
  float acc = dot4(m4[seg * 2], y4[seg * 2]) + dot4(m4[seg * 2 + 1], y4[seg * 2 + 1]);
#pragma unroll
  for (int m = 1; m < 64; m <<= 1) acc += __shfl_xor(acc, m);
  if (lane == 0) smo[w] = acc;
  __syncthreads();
  if (t < 4) out[bid * 4 + t] = smo[2 * t] + smo[2 * t + 1] + bias2[bid * 4 + t];
}

// ---- shared phase-1 body ----
__device__ __forceinline__ void phase1(const float* __restrict__ x, const float* __restrict__ W,
                                       const float* __restrict__ inb, const float* __restrict__ Wout,
                                       const float* __restrict__ bout, float* sh, float* ws,
                                       int bid, int t) {
  float* bias2 = ws + WS_B2;
  float* M2 = ws + WS_M2;
  float* ypart = ws + WS_YP;
  float* mpart = ws + WS_MP;
  float* lpart = ws + WS_LP;
  float* xs = sh;            // 256
  float* qls = sh + 256;     // 256
  float* kqls = sh + 512;    // 1024
  float* c4ls = sh + 1536;   // 4
  float* red2 = sh + 1540;   // 2048 (aliases yls; dead before B)
  float* yls = sh + 1540;    // 8192+64

  const int lane = t & 63, w = t >> 6;
  const int r0 = bid * 128 + w * 16;
  float4 xvA[8], xvB[8];
#pragma unroll
  for (int r = 0; r < 8; ++r)
    xvA[r] = *(const float4*)&x[(size_t)(r0 + r) * 256 + lane * 4];
#pragma unroll
  for (int r = 0; r < 8; ++r)
    xvB[r] = *(const float4*)&x[(size_t)(r0 + 8 + r) * 256 + lane * 4];

  make_kq(x, W, inb, xs, qls, kqls, c4ls, red2, t);
  phaseB_core(xvA, xvB, kqls, c4ls, ypart, mpart, lpart, yls, bid, t);

  if (bid >= 128) {
    phaseA_m2(W, Wout, M2, sh, bid - 128, t);  // sh[0..511]; disjoint from yls
    if (bid >= 240) {
      __syncthreads();  // m2's LDS reads done before b2 overwrites sh
      phaseA_b2(Wout, inb, bout, bias2, sh, bid - 240, t);
    }
  }
}

// ---- Cooperative single-launch ----
__global__ void __launch_bounds__(512, 1) mha_one(const float* __restrict__ x,
                                                  const float* __restrict__ W,
                                                  const float* __restrict__ inb,
                                                  const float* __restrict__ Wout,
                                                  const float* __restrict__ bout,
                                                  float* __restrict__ out,
                                                  float* __restrict__ ws) {
  __shared__ __align__(16) float sh[9796];
  const int t = threadIdx.x, bid = blockIdx.x;
  cg::grid_group grid = cg::this_grid();

  phase1(x, W, inb, Wout, bout, sh, ws, bid, t);
  grid.sync();  // the single all-to-all barrier (B -> C)
  if (bid >= 64) return;
  phaseC(ws + WS_YP, ws + WS_MP, ws + WS_LP, ws + WS_YV, sh, bid, t);
  sig_rel((int*)(ws + WS_CNT));
  spin_acq((int*)(ws + WS_CNT), 64);  // 64 one-lane acquire-load polls
  phaseD4(ws + WS_M2, ws + WS_YV, ws + WS_B2, out, sh, bid, t);
}

// ---- Fallback chain (no coop): 3 launches ----
__global__ void __launch_bounds__(512) fb_1(const float* __restrict__ x, const float* __restrict__ W,
                                            const float* __restrict__ inb, const float* __restrict__ Wout,
                                            const float* __restrict__ bout, float* __restrict__ ws) {
  __shared__ __align__(16) float sh[9796];
  phase1(x, W, inb, Wout, bout, sh, ws, blockIdx.x, threadIdx.x);
}
__global__ void __launch_bounds__(512) fb_2(float* __restrict__ ws) {
  __shared__ __align__(16) float sh[1280];
  phaseC(ws + WS_YP, ws + WS_MP, ws + WS_LP, ws + WS_YV, sh, blockIdx.x, threadIdx.x);
}
__global__ void __launch_bounds__(512) fb_3(float* __restrict__ out, float* __restrict__ ws) {
  __shared__ __align__(16) float sh[1056];
  phaseD4(ws + WS_M2, ws + WS_YV, ws + WS_B2, out, sh, blockIdx.x, threadIdx.x);
}

extern "C" void kernel_launch(void* const* d_in, const int* in_sizes, int n_in,
                              void* d_out, int out_size, void* d_ws, size_t ws_size,
                              hipStream_t stream) {
  const float* x = (const float*)d_in[0];
  const float* W = (const float*)d_in[1];
  const float* inb = (const float*)d_in[2];
  const float* Wout = (const float*)d_in[3];
  const float* bout = (const float*)d_in[4];
  float* out = (float*)d_out;
  float* ws = (float*)d_ws;

  hipMemsetAsync((void*)(ws + WS_CNT), 0, 16, stream);

  int dev = 0;
  (void)hipGetDevice(&dev);
  int coopAttr = 0, ncu = 0, occ = 0;
  bool coop = (hipDeviceGetAttribute(&coopAttr, hipDeviceAttributeCooperativeLaunch, dev) == hipSuccess) &&
              coopAttr != 0;
  coop = coop &&
         (hipDeviceGetAttribute(&ncu, hipDeviceAttributeMultiprocessorCount, dev) == hipSuccess);
  coop = coop &&
         (hipOccupancyMaxActiveBlocksPerMultiprocessor(&occ, mha_one, 512, 0) == hipSuccess);
  coop = coop && (occ * ncu >= NBLK);

  if (coop) {
    void* args[] = {(void*)&x, (void*)&W, (void*)&inb, (void*)&Wout,
                    (void*)&bout, (void*)&out, (void*)&ws};
    if (hipLaunchCooperativeKernel((const void*)mha_one, dim3(NBLK), dim3(512),
                                   args, 0, stream) == hipSuccess)
      return;
  }
  fb_1<<<NBLK, 512, 0, stream>>>(x, W, inb, Wout, bout, ws);
  fb_2<<<64, 512, 0, stream>>>(ws);
  fb_3<<<64, 512, 0, stream>>>(out, ws);
}

// Round 11
// 36.045 us; speedup vs baseline: 1.5142x; 1.5142x over previous
//
#include <hip/hip_runtime.h>

#define NBLK 256
// float offsets into ws
#define WS_MP   0        // mpart 4*256
#define WS_LP   1024     // lpart 4*256
#define WS_YV   2048     // yv 1024
#define WS_B2   3072     // bias2 256
#define WS_KQ   3328     // kq 1024
#define WS_C4   4352     // c4 4 (pad 64)
#define WS_M2   4416     // M2 256*1024
#define WS_YP   266560   // ypart 256*1024
#define WS_CNT  528704   // flags: A[16] B[256] C[64] M[128]

__device__ __forceinline__ float dot4(float4 a, float4 b) {
  return a.x * b.x + a.y * b.y + a.z * b.z + a.w * b.w;
}

// ---- sync primitives: release store + wave-parallel acquire-load poll (NO RMWs) ----
__device__ __forceinline__ void set_flag(int* slot, int t) {
  __threadfence();
  __syncthreads();
  if (t == 0) __hip_atomic_store(slot, 1, __ATOMIC_RELEASE, __HIP_MEMORY_SCOPE_AGENT);
}
__device__ __forceinline__ void poll_flags(const int* flags, int n, int t) {
  const int idx = t & (n - 1);  // n is a power of two <= 512
  for (;;) {
    int v = __hip_atomic_load((int*)&flags[idx], __ATOMIC_RELAXED, __HIP_MEMORY_SCOPE_AGENT);
    if (__syncthreads_and(v != 0)) break;
    __builtin_amdgcn_s_sleep(2);
  }
  __threadfence();
}

// ---- Phase A (16 blocks): q_h redundant per (h,qt), kq quarter, c4 ----
__device__ __forceinline__ void phaseA_kq(const float* __restrict__ x, const float* __restrict__ W,
                                          const float* __restrict__ inb, float* __restrict__ kq,
                                          float* __restrict__ c4, float* sh, int bid, int t) {
  float* xs = sh;          // 256
  float* qls = sh + 256;   // 64
  float* red = sh + 320;   // 512
  const int lane = t & 63, w = t >> 6;
  const int h = bid >> 2, qt = bid & 3;
  if (t < 256) xs[t] = x[t];
  __syncthreads();
  const float4 xv = *(const float4*)&xs[lane * 4];
#pragma unroll
  for (int k = 0; k < 8; ++k) {
    const int eloc = w * 8 + k;
    const int row = h * 64 + eloc;
    float4 wv = *(const float4*)&W[(size_t)row * 256 + lane * 4];
    float p = dot4(wv, xv);
#pragma unroll
    for (int m = 1; m < 64; m <<= 1) p += __shfl_xor(p, m);
    if (lane == 0) qls[eloc] = p + inb[row];
  }
  __syncthreads();
  const int cl = t & 63, ds = t >> 6;
  float acc = 0.f;
#pragma unroll
  for (int d2 = 0; d2 < 8; ++d2) {
    const int d = ds * 8 + d2;
    acc += W[(size_t)(256 + h * 64 + d) * 256 + qt * 64 + cl] * qls[d];
  }
  red[ds * 64 + cl] = acc;
  __syncthreads();
  if (ds == 0) {
    float s = 0.f;
#pragma unroll
    for (int i = 0; i < 8; ++i) s += red[i * 64 + cl];
    kq[h * 256 + qt * 64 + cl] = s;
  }
  if (qt == 0 && t < 64) {
    float v = qls[t] * inb[256 + h * 64 + t];
#pragma unroll
    for (int m = 1; m < 64; m <<= 1) v += __shfl_xor(v, m);
    if (t == 0) c4[h] = v;
  }
}

// ---- M2 tile + 2 bias2 outputs (b2 in 0..127) ----
__device__ __forceinline__ void phaseM2b(const float* __restrict__ W, const float* __restrict__ Wout,
                                         const float* __restrict__ inb, const float* __restrict__ bout,
                                         float* __restrict__ M2, float* __restrict__ bias2,
                                         float* sh, int b2, int t) {
  float* wout_t = sh;  // [8][64]
  const int tile = b2 >> 1, sub = b2 & 1;
  const int h = tile >> 4, e0 = (tile & 15) * 16 + sub * 8;
  {
    const int e = t >> 6, d = t & 63;
    wout_t[e * 64 + d] = Wout[(size_t)(e0 + e) * 256 + h * 64 + d];
  }
  __syncthreads();
  const int c = t & 255, eh = t >> 8;
  float acc[4] = {0.f, 0.f, 0.f, 0.f};
#pragma unroll 8
  for (int d = 0; d < 64; ++d) {
    const float wv = W[(size_t)(512 + h * 64 + d) * 256 + c];
#pragma unroll
    for (int e = 0; e < 4; ++e) acc[e] += wv * wout_t[(eh * 4 + e) * 64 + d];
  }
#pragma unroll
  for (int e = 0; e < 4; ++e)
    M2[(size_t)(e0 + eh * 4 + e) * 1024 + h * 256 + c] = acc[e];
  __syncthreads();
  // bias2 outputs 2*b2 + {0,1}
  float* red = sh;  // 512
  const int oi = t >> 8, seg = t & 255;
  const int e = 2 * b2 + oi;
  red[oi * 256 + seg] = Wout[(size_t)e * 256 + seg] * inb[512 + seg];
  __syncthreads();
  for (int s = 128; s > 0; s >>= 1) {
    if (seg < s) red[oi * 256 + seg] += red[oi * 256 + seg + s];
    __syncthreads();
  }
  if (t < 2) bias2[2 * b2 + t] = red[t * 256] + bout[2 * b2 + t];
}

// ---- Phase B (verified R8 core) ----
__device__ __forceinline__ float bscore(float4 xv, float4 kq0, float4 kq1, float4 kq2,
                                        float4 kq3, float c4v, int lane) {
  float p0 = dot4(xv, kq0), p1 = dot4(xv, kq1), p2 = dot4(xv, kq2), p3 = dot4(xv, kq3);
  const bool b1 = (lane & 2) != 0;
  float keep0 = b1 ? p2 : p0, send0 = b1 ? p0 : p2;
  keep0 += __shfl_xor(send0, 2);
  float keep1 = b1 ? p3 : p1, send1 = b1 ? p1 : p3;
  keep1 += __shfl_xor(send1, 2);
  const bool b0 = (lane & 1) != 0;
  float vv = b0 ? keep1 : keep0, sv = b0 ? keep0 : keep1;
  vv += __shfl_xor(sv, 1);
  vv += __shfl_xor(vv, 4);
  vv += __shfl_xor(vv, 8);
  vv += __shfl_xor(vv, 16);
  vv += __shfl_xor(vv, 32);
  return (vv + c4v) * 0.125f;
}

__device__ __forceinline__ void phaseB_core(const float4* xvA, const float4* xvB,
                                            const float* __restrict__ kq, const float* __restrict__ c4,
                                            float* __restrict__ ypart, float* __restrict__ mpart,
                                            float* __restrict__ lpart, float* yls, int bid, int t) {
  float* sml = yls + 8192;  // 32
  float* sll = yls + 8224;  // 32
  const int lane = t & 63, w = t >> 6;
  const int hme = lane & 3;
  const float4 kq0 = *(const float4*)&kq[0 * 256 + lane * 4];
  const float4 kq1 = *(const float4*)&kq[1 * 256 + lane * 4];
  const float4 kq2 = *(const float4*)&kq[2 * 256 + lane * 4];
  const float4 kq3 = *(const float4*)&kq[3 * 256 + lane * 4];
  const float c4v = c4[hme];

  float vA[8];
#pragma unroll
  for (int r = 0; r < 8; ++r) vA[r] = bscore(xvA[r], kq0, kq1, kq2, kq3, c4v, lane);
  float m = vA[0];
#pragma unroll
  for (int r = 1; r < 8; ++r) m = fmaxf(m, vA[r]);

  float l = 0.f;
  float4 a[4];
#pragma unroll
  for (int k = 0; k < 4; ++k) a[k] = (float4){0.f, 0.f, 0.f, 0.f};
#pragma unroll
  for (int r = 0; r < 8; ++r) {
    const float e0 = __expf(vA[r] - m);
    l += e0;
    const float e1 = __shfl_xor(e0, 1);
    const float e2 = __shfl_xor(e0, 2);
    const float e3 = __shfl_xor(e0, 3);
    a[0].x += e0 * xvA[r].x; a[0].y += e0 * xvA[r].y; a[0].z += e0 * xvA[r].z; a[0].w += e0 * xvA[r].w;
    a[1].x += e1 * xvA[r].x; a[1].y += e1 * xvA[r].y; a[1].z += e1 * xvA[r].z; a[1].w += e1 * xvA[r].w;
    a[2].x += e2 * xvA[r].x; a[2].y += e2 * xvA[r].y; a[2].z += e2 * xvA[r].z; a[2].w += e2 * xvA[r].w;
    a[3].x += e3 * xvA[r].x; a[3].y += e3 * xvA[r].y; a[3].z += e3 * xvA[r].z; a[3].w += e3 * xvA[r].w;
  }

  float vB[8];
#pragma unroll
  for (int r = 0; r < 8; ++r) vB[r] = bscore(xvB[r], kq0, kq1, kq2, kq3, c4v, lane);
  float mB = vB[0];
#pragma unroll
  for (int r = 1; r < 8; ++r) mB = fmaxf(mB, vB[r]);

  {  // online merge with per-head rescale factors (verified R8)
    const float mN = fmaxf(m, mB);
    const float fown = __expf(m - mN);
    l *= fown;
    const float f1 = __shfl_xor(fown, 1);
    const float f2 = __shfl_xor(fown, 2);
    const float f3 = __shfl_xor(fown, 3);
    a[0].x *= fown; a[0].y *= fown; a[0].z *= fown; a[0].w *= fown;
    a[1].x *= f1;   a[1].y *= f1;   a[1].z *= f1;   a[1].w *= f1;
    a[2].x *= f2;   a[2].y *= f2;   a[2].z *= f2;   a[2].w *= f2;
    a[3].x *= f3;   a[3].y *= f3;   a[3].z *= f3;   a[3].w *= f3;
    m = mN;
  }
#pragma unroll
  for (int r = 0; r < 8; ++r) {
    const float e0 = __expf(vB[r] - m);
    l += e0;
    const float e1 = __shfl_xor(e0, 1);
    const float e2 = __shfl_xor(e0, 2);
    const float e3 = __shfl_xor(e0, 3);
    a[0].x += e0 * xvB[r].x; a[0].y += e0 * xvB[r].y; a[0].z += e0 * xvB[r].z; a[0].w += e0 * xvB[r].w;
    a[1].x += e1 * xvB[r].x; a[1].y += e1 * xvB[r].y; a[1].z += e1 * xvB[r].z; a[1].w += e1 * xvB[r].w;
    a[2].x += e2 * xvB[r].x; a[2].y += e2 * xvB[r].y; a[2].z += e2 * xvB[r].z; a[2].w += e2 * xvB[r].w;
    a[3].x += e3 * xvB[r].x; a[3].y += e3 * xvB[r].y; a[3].z += e3 * xvB[r].z; a[3].w += e3 * xvB[r].w;
  }

  __syncthreads();
  if (lane < 4) { sml[w * 4 + lane] = m; sll[w * 4 + lane] = l; }
  __syncthreads();

#pragma unroll
  for (int k = 0; k < 4; ++k) {
    const int h = hme ^ k;
    float mb = sml[h];
#pragma unroll
    for (int i = 1; i < 8; ++i) mb = fmaxf(mb, sml[i * 4 + h]);
    const float f = __expf(sml[w * 4 + h] - mb);
    float4 av;
    av.x = a[k].x * f; av.y = a[k].y * f; av.z = a[k].z * f; av.w = a[k].w * f;
    *(float4*)&yls[w * 1024 + h * 256 + lane * 4] = av;
  }
  __syncthreads();

  if (t < 4) {
    float mb = sml[t];
#pragma unroll
    for (int i = 1; i < 8; ++i) mb = fmaxf(mb, sml[i * 4 + t]);
    float lb = 0.f;
#pragma unroll
    for (int i = 0; i < 8; ++i) lb += sll[i * 4 + t] * __expf(sml[i * 4 + t] - mb);
    mpart[t * NBLK + bid] = mb;
    lpart[t * NBLK + bid] = lb;
  }
  float* yp = &ypart[(size_t)bid * 1024];
#pragma unroll
  for (int o = t; o < 1024; o += 512) {
    float s = 0.f;
#pragma unroll
    for (int i = 0; i < 8; ++i) s += yls[i * 1024 + o];
    yp[o] = s;
  }
}

// ---- Phase C (verified): 64 blocks, 16 outputs each ----
__device__ __forceinline__ void phaseC(const float* __restrict__ ypart, const float* __restrict__ mpart,
                                       const float* __restrict__ lpart, float* __restrict__ yv,
                                       float* sh, int bid, int t) {
  float* mred = sh;           // 256
  float* scales = sh + 256;   // 256
  float* lred = sh + 512;     // 256
  float* sred = sh + 768;     // 512
  const int h = bid >> 4;
  const int o0 = bid * 16;
  if (t < 256) mred[t] = mpart[h * 256 + t];
  __syncthreads();
  for (int s = 128; s > 0; s >>= 1) {
    if (t < s) mred[t] = fmaxf(mred[t], mred[t + s]);
    __syncthreads();
  }
  const float mg = mred[0];
  if (t < 256) {
    const float sc = __expf(mpart[h * 256 + t] - mg);
    scales[t] = sc;
    lred[t] = lpart[h * 256 + t] * sc;
  }
  __syncthreads();
  for (int s = 128; s > 0; s >>= 1) {
    if (t < s) lred[t] += lred[t + s];
    __syncthreads();
  }
  const float inv = 1.0f / lred[0];
  const int ol = t & 15, bg = t >> 4;
  float s = 0.f;
#pragma unroll
  for (int j = 0; j < 8; ++j) {
    const int b = bg * 8 + j;
    s += ypart[(size_t)b * 1024 + o0 + ol] * scales[b];
  }
  sred[bg * 16 + ol] = s;
  __syncthreads();
  if (t < 16) {
    float tot = 0.f;
#pragma unroll
    for (int g = 0; g < 32; ++g) tot += sred[g * 16 + t];
    yv[o0 + t] = tot * inv;
  }
}

// ---- Phase D4 (verified): 64 blocks, 4 outputs each ----
__device__ __forceinline__ void phaseD4(const float* __restrict__ M2, const float* __restrict__ yv,
                                        const float* __restrict__ bias2, float* __restrict__ out,
                                        float* sh, int bid, int t) {
  float* yls2 = sh;          // 1024
  float* smo = sh + 1024;    // 8
  const int lane = t & 63, w = t >> 6;
  for (int i = t; i < 1024; i += 512) yls2[i] = yv[i];
  __syncthreads();
  const int seg = t & 127;
  const int e = bid * 4 + (t >> 7);
  const float4* m4 = (const float4*)&M2[(size_t)e * 1024];
  const float4* y4 = (const float4*)yls2;
  float acc = dot4(m4[seg * 2], y4[seg * 2]) + dot4(m4[seg * 2 + 1], y4[seg * 2 + 1]);
#pragma unroll
  for (int m = 1; m < 64; m <<= 1) acc += __shfl_xor(acc, m);
  if (lane == 0) smo[w] = acc;
  __syncthreads();
  if (t < 4) out[bid * 4 + t] = smo[2 * t] + smo[2 * t + 1] + bias2[bid * 4 + t];
}

// ---- Single cooperative launch (coop only for co-residency; no grid.sync) ----
__global__ void __launch_bounds__(512, 1) mha_one(const float* __restrict__ x,
                                                  const float* __restrict__ W,
                                                  const float* __restrict__ inb,
                                                  const float* __restrict__ Wout,
                                                  const float* __restrict__ bout,
                                                  float* __restrict__ out,
                                                  float* __restrict__ ws) {
  __shared__ __align__(16) float sh[8256];
  const int t = threadIdx.x, bid = blockIdx.x;
  const int lane = t & 63, w = t >> 6;
  int* flagA = (int*)(ws + WS_CNT);
  int* flagB = flagA + 16;
  int* flagC = flagB + 256;
  int* flagM = flagC + 64;

  const int r0 = bid * 128 + w * 16;
  float4 xvA[8], xvB[8];

  if (bid >= 16) {
#pragma unroll
    for (int r = 0; r < 8; ++r)
      xvA[r] = *(const float4*)&x[(size_t)(r0 + r) * 256 + lane * 4];
#pragma unroll
    for (int r = 0; r < 8; ++r)
      xvB[r] = *(const float4*)&x[(size_t)(r0 + 8 + r) * 256 + lane * 4];
  } else {
    phaseA_kq(x, W, inb, ws + WS_KQ, ws + WS_C4, sh, bid, t);
    set_flag(&flagA[bid], t);
#pragma unroll
    for (int r = 0; r < 8; ++r)
      xvA[r] = *(const float4*)&x[(size_t)(r0 + r) * 256 + lane * 4];
#pragma unroll
    for (int r = 0; r < 8; ++r)
      xvB[r] = *(const float4*)&x[(size_t)(r0 + 8 + r) * 256 + lane * 4];
  }

  poll_flags(flagA, 16, t);
  phaseB_core(xvA, xvB, ws + WS_KQ, ws + WS_C4, ws + WS_YP, ws + WS_MP, ws + WS_LP, sh, bid, t);
  set_flag(&flagB[bid], t);

  if (bid >= 128) {
    phaseM2b(W, Wout, inb, bout, ws + WS_M2, ws + WS_B2, sh, bid - 128, t);
    set_flag(&flagM[bid - 128], t);
    return;
  }
  if (bid >= 64) return;

  poll_flags(flagB, 256, t);
  phaseC(ws + WS_YP, ws + WS_MP, ws + WS_LP, ws + WS_YV, sh, bid, t);
  set_flag(&flagC[bid], t);
  poll_flags(flagC, 64, t);
  poll_flags(flagM, 128, t);
  phaseD4(ws + WS_M2, ws + WS_YV, ws + WS_B2, out, sh, bid, t);
}

// ---- Fallback chain (no coop): 4 launches, no flags ----
__global__ void __launch_bounds__(512) fb_A(const float* __restrict__ x, const float* __restrict__ W,
                                            const float* __restrict__ inb, float* __restrict__ ws) {
  __shared__ __align__(16) float sh[832];
  phaseA_kq(x, W, inb, ws + WS_KQ, ws + WS_C4, sh, blockIdx.x, threadIdx.x);
}
__global__ void __launch_bounds__(512) fb_B(const float* __restrict__ x, float* __restrict__ ws) {
  __shared__ __align__(16) float sh[8256];
  const int bid = blockIdx.x, t = threadIdx.x;
  const int lane = t & 63, w = t >> 6;
  const int r0 = bid * 128 + w * 16;
  float4 xvA[8], xvB[8];
#pragma unroll
  for (int r = 0; r < 8; ++r)
    xvA[r] = *(const float4*)&x[(size_t)(r0 + r) * 256 + lane * 4];
#pragma unroll
  for (int r = 0; r < 8; ++r)
    xvB[r] = *(const float4*)&x[(size_t)(r0 + 8 + r) * 256 + lane * 4];
  phaseB_core(xvA, xvB, ws + WS_KQ, ws + WS_C4, ws + WS_YP, ws + WS_MP, ws + WS_LP, sh, bid, t);
}
__global__ void __launch_bounds__(512) fb_CM(const float* __restrict__ W, const float* __restrict__ Wout,
                                             const float* __restrict__ inb, const float* __restrict__ bout,
                                             float* __restrict__ ws) {
  __shared__ __align__(16) float sh[1280];
  const int bid = blockIdx.x, t = threadIdx.x;
  if (bid < 64) phaseC(ws + WS_YP, ws + WS_MP, ws + WS_LP, ws + WS_YV, sh, bid, t);
  else phaseM2b(W, Wout, inb, bout, ws + WS_M2, ws + WS_B2, sh, bid - 64, t);
}
__global__ void __launch_bounds__(512) fb_D(float* __restrict__ out, float* __restrict__ ws) {
  __shared__ __align__(16) float sh[1056];
  phaseD4(ws + WS_M2, ws + WS_YV, ws + WS_B2, out, sh, blockIdx.x, threadIdx.x);
}

extern "C" void kernel_launch(void* const* d_in, const int* in_sizes, int n_in,
                              void* d_out, int out_size, void* d_ws, size_t ws_size,
                              hipStream_t stream) {
  const float* x = (const float*)d_in[0];
  const float* W = (const float*)d_in[1];
  const float* inb = (const float*)d_in[2];
  const float* Wout = (const float*)d_in[3];
  const float* bout = (const float*)d_in[4];
  float* out = (float*)d_out;
  float* ws = (float*)d_ws;

  // zero all flags (A16+B256+C64+M128 = 464 ints)
  hipMemsetAsync((void*)(ws + WS_CNT), 0, 2048, stream);

  int dev = 0;
  (void)hipGetDevice(&dev);
  int coopAttr = 0, ncu = 0, occ = 0;
  bool coop = (hipDeviceGetAttribute(&coopAttr, hipDeviceAttributeCooperativeLaunch, dev) == hipSuccess) &&
              coopAttr != 0;
  coop = coop &&
         (hipDeviceGetAttribute(&ncu, hipDeviceAttributeMultiprocessorCount, dev) == hipSuccess);
  coop = coop &&
         (hipOccupancyMaxActiveBlocksPerMultiprocessor(&occ, mha_one, 512, 0) == hipSuccess);
  coop = coop && (occ * ncu >= NBLK);

  if (coop) {
    void* args[] = {(void*)&x, (void*)&W, (void*)&inb, (void*)&Wout,
                    (void*)&bout, (void*)&out, (void*)&ws};
    if (hipLaunchCooperativeKernel((const void*)mha_one, dim3(NBLK), dim3(512),
                                   args, 0, stream) == hipSuccess)
      return;
  }
  fb_A<<<16, 512, 0, stream>>>(x, W, inb, ws);
  fb_B<<<NBLK, 512, 0, stream>>>(x, ws);
  fb_CM<<<192, 512, 0, stream>>>(W, Wout, inb, bout, ws);
  fb_D<<<64, 512, 0, stream>>>(out, ws);
}

// Round 12
// 35.903 us; speedup vs baseline: 1.5202x; 1.0040x over previous
//
#include <hip/hip_runtime.h>
#include <hip/hip_cooperative_groups.h>
namespace cg = cooperative_groups;

#define NBLK 256
// float offsets into ws
#define WS_MP   0        // mpart 4*256
#define WS_LP   1024     // lpart 4*256
#define WS_YV   2048     // yv 1024 (already /l per head)
#define WS_CTX  3072     // ctx 256
#define WS_KQ   3328     // kq 1024
#define WS_C4   4352     // c4 4 (pad 64)
#define WS_YP   4416     // ypart 256*1024
#define WS_CNT  266560   // flags: A[16] C[64] X[64]

__device__ __forceinline__ float dot4(float4 a, float4 b) {
  return a.x * b.x + a.y * b.y + a.z * b.z + a.w * b.w;
}

// ---- sync primitives (R11-proven correct): release store + acquire-load poll ----
__device__ __forceinline__ void set_flag(int* slot, int t) {
  __threadfence();
  __syncthreads();
  if (t == 0) __hip_atomic_store(slot, 1, __ATOMIC_RELEASE, __HIP_MEMORY_SCOPE_AGENT);
}
__device__ __forceinline__ void poll_flags(const int* flags, int n, int t) {
  const int idx = t & (n - 1);  // n power of two <= 512
  for (;;) {
    int v = __hip_atomic_load((int*)&flags[idx], __ATOMIC_RELAXED, __HIP_MEMORY_SCOPE_AGENT);
    if (__syncthreads_and(v != 0)) break;
    __builtin_amdgcn_s_sleep(2);
  }
  __threadfence();
}

// ---- Phase A (16 blocks): q_h redundant per (h,qt), kq quarter, c4 (verified R8/R11) ----
__device__ __forceinline__ void phaseA_kq(const float* __restrict__ x, const float* __restrict__ W,
                                          const float* __restrict__ inb, float* __restrict__ kq,
                                          float* __restrict__ c4, float* sh, int bid, int t) {
  float* xs = sh;          // 256
  float* qls = sh + 256;   // 64
  float* red = sh + 320;   // 512
  const int lane = t & 63, w = t >> 6;
  const int h = bid >> 2, qt = bid & 3;
  if (t < 256) xs[t] = x[t];
  __syncthreads();
  const float4 xv = *(const float4*)&xs[lane * 4];
#pragma unroll
  for (int k = 0; k < 8; ++k) {
    const int eloc = w * 8 + k;
    const int row = h * 64 + eloc;
    float4 wv = *(const float4*)&W[(size_t)row * 256 + lane * 4];
    float p = dot4(wv, xv);
#pragma unroll
    for (int m = 1; m < 64; m <<= 1) p += __shfl_xor(p, m);
    if (lane == 0) qls[eloc] = p + inb[row];
  }
  __syncthreads();
  const int cl = t & 63, ds = t >> 6;
  float acc = 0.f;
#pragma unroll
  for (int d2 = 0; d2 < 8; ++d2) {
    const int d = ds * 8 + d2;
    acc += W[(size_t)(256 + h * 64 + d) * 256 + qt * 64 + cl] * qls[d];
  }
  red[ds * 64 + cl] = acc;
  __syncthreads();
  if (ds == 0) {
    float s = 0.f;
#pragma unroll
    for (int i = 0; i < 8; ++i) s += red[i * 64 + cl];
    kq[h * 256 + qt * 64 + cl] = s;
  }
  if (qt == 0 && t < 64) {
    float v = qls[t] * inb[256 + h * 64 + t];
#pragma unroll
    for (int m = 1; m < 64; m <<= 1) v += __shfl_xor(v, m);
    if (t == 0) c4[h] = v;
  }
}

// ---- Phase B: 16 rows/wave, single max (no online merge) ----
__device__ __forceinline__ float bscore(float4 xv, float4 kq0, float4 kq1, float4 kq2,
                                        float4 kq3, float c4v, int lane) {
  float p0 = dot4(xv, kq0), p1 = dot4(xv, kq1), p2 = dot4(xv, kq2), p3 = dot4(xv, kq3);
  const bool b1 = (lane & 2) != 0;
  float keep0 = b1 ? p2 : p0, send0 = b1 ? p0 : p2;
  keep0 += __shfl_xor(send0, 2);
  float keep1 = b1 ? p3 : p1, send1 = b1 ? p1 : p3;
  keep1 += __shfl_xor(send1, 2);
  const bool b0 = (lane & 1) != 0;
  float vv = b0 ? keep1 : keep0, sv = b0 ? keep0 : keep1;
  vv += __shfl_xor(sv, 1);
  vv += __shfl_xor(vv, 4);
  vv += __shfl_xor(vv, 8);
  vv += __shfl_xor(vv, 16);
  vv += __shfl_xor(vv, 32);
  return (vv + c4v) * 0.125f;
}

__device__ __forceinline__ void phaseB_core(const float4* xvA, const float4* xvB,
                                            const float* __restrict__ kq, const float* __restrict__ c4,
                                            float* __restrict__ ypart, float* __restrict__ mpart,
                                            float* __restrict__ lpart, float* yls, int bid, int t) {
  float* sml = yls + 8192;  // 32
  float* sll = yls + 8224;  // 32
  const int lane = t & 63, w = t >> 6;
  const int hme = lane & 3;
  const float4 kq0 = *(const float4*)&kq[0 * 256 + lane * 4];
  const float4 kq1 = *(const float4*)&kq[1 * 256 + lane * 4];
  const float4 kq2 = *(const float4*)&kq[2 * 256 + lane * 4];
  const float4 kq3 = *(const float4*)&kq[3 * 256 + lane * 4];
  const float c4v = c4[hme];

  float vA[8], vB[8];
#pragma unroll
  for (int r = 0; r < 8; ++r) vA[r] = bscore(xvA[r], kq0, kq1, kq2, kq3, c4v, lane);
#pragma unroll
  for (int r = 0; r < 8; ++r) vB[r] = bscore(xvB[r], kq0, kq1, kq2, kq3, c4v, lane);

  float m = vA[0];
#pragma unroll
  for (int r = 1; r < 8; ++r) m = fmaxf(m, vA[r]);
#pragma unroll
  for (int r = 0; r < 8; ++r) m = fmaxf(m, vB[r]);

  float l = 0.f;
  float4 a[4];
#pragma unroll
  for (int k = 0; k < 4; ++k) a[k] = (float4){0.f, 0.f, 0.f, 0.f};
#pragma unroll
  for (int r = 0; r < 8; ++r) {
    const float e0 = __expf(vA[r] - m);
    l += e0;
    const float e1 = __shfl_xor(e0, 1);
    const float e2 = __shfl_xor(e0, 2);
    const float e3 = __shfl_xor(e0, 3);
    a[0].x += e0 * xvA[r].x; a[0].y += e0 * xvA[r].y; a[0].z += e0 * xvA[r].z; a[0].w += e0 * xvA[r].w;
    a[1].x += e1 * xvA[r].x; a[1].y += e1 * xvA[r].y; a[1].z += e1 * xvA[r].z; a[1].w += e1 * xvA[r].w;
    a[2].x += e2 * xvA[r].x; a[2].y += e2 * xvA[r].y; a[2].z += e2 * xvA[r].z; a[2].w += e2 * xvA[r].w;
    a[3].x += e3 * xvA[r].x; a[3].y += e3 * xvA[r].y; a[3].z += e3 * xvA[r].z; a[3].w += e3 * xvA[r].w;
  }
#pragma unroll
  for (int r = 0; r < 8; ++r) {
    const float e0 = __expf(vB[r] - m);
    l += e0;
    const float e1 = __shfl_xor(e0, 1);
    const float e2 = __shfl_xor(e0, 2);
    const float e3 = __shfl_xor(e0, 3);
    a[0].x += e0 * xvB[r].x; a[0].y += e0 * xvB[r].y; a[0].z += e0 * xvB[r].z; a[0].w += e0 * xvB[r].w;
    a[1].x += e1 * xvB[r].x; a[1].y += e1 * xvB[r].y; a[1].z += e1 * xvB[r].z; a[1].w += e1 * xvB[r].w;
    a[2].x += e2 * xvB[r].x; a[2].y += e2 * xvB[r].y; a[2].z += e2 * xvB[r].z; a[2].w += e2 * xvB[r].w;
    a[3].x += e3 * xvB[r].x; a[3].y += e3 * xvB[r].y; a[3].z += e3 * xvB[r].z; a[3].w += e3 * xvB[r].w;
  }

  __syncthreads();
  if (lane < 4) { sml[w * 4 + lane] = m; sll[w * 4 + lane] = l; }
  __syncthreads();

#pragma unroll
  for (int k = 0; k < 4; ++k) {
    const int h = hme ^ k;
    float mb = sml[h];
#pragma unroll
    for (int i = 1; i < 8; ++i) mb = fmaxf(mb, sml[i * 4 + h]);
    const float f = __expf(sml[w * 4 + h] - mb);
    float4 av;
    av.x = a[k].x * f; av.y = a[k].y * f; av.z = a[k].z * f; av.w = a[k].w * f;
    *(float4*)&yls[w * 1024 + h * 256 + lane * 4] = av;
  }
  __syncthreads();

  if (t < 4) {
    float mb = sml[t];
#pragma unroll
    for (int i = 1; i < 8; ++i) mb = fmaxf(mb, sml[i * 4 + t]);
    float lb = 0.f;
#pragma unroll
    for (int i = 0; i < 8; ++i) lb += sll[i * 4 + t] * __expf(sml[i * 4 + t] - mb);
    mpart[t * NBLK + bid] = mb;
    lpart[t * NBLK + bid] = lb;
  }
  float* yp = &ypart[(size_t)bid * 1024];
#pragma unroll
  for (int o = t; o < 1024; o += 512) {
    float s = 0.f;
#pragma unroll
    for (int i = 0; i < 8; ++i) s += yls[i * 1024 + o];
    yp[o] = s;
  }
}

// ---- Phase C (verified): 64 blocks, 16 yv outputs each, 1/l folded ----
__device__ __forceinline__ void phaseC(const float* __restrict__ ypart, const float* __restrict__ mpart,
                                       const float* __restrict__ lpart, float* __restrict__ yv,
                                       float* sh, int bid, int t) {
  float* mred = sh;           // 256
  float* scales = sh + 256;   // 256
  float* lred = sh + 512;     // 256
  float* sred = sh + 768;     // 512
  const int h = bid >> 4;
  const int o0 = bid * 16;
  if (t < 256) mred[t] = mpart[h * 256 + t];
  __syncthreads();
  for (int s = 128; s > 0; s >>= 1) {
    if (t < s) mred[t] = fmaxf(mred[t], mred[t + s]);
    __syncthreads();
  }
  const float mg = mred[0];
  if (t < 256) {
    const float sc = __expf(mpart[h * 256 + t] - mg);
    scales[t] = sc;
    lred[t] = lpart[h * 256 + t] * sc;
  }
  __syncthreads();
  for (int s = 128; s > 0; s >>= 1) {
    if (t < s) lred[t] += lred[t + s];
    __syncthreads();
  }
  const float inv = 1.0f / lred[0];
  const int ol = t & 15, bg = t >> 4;
  float s = 0.f;
#pragma unroll
  for (int j = 0; j < 8; ++j) {
    const int b = bg * 8 + j;
    s += ypart[(size_t)b * 1024 + o0 + ol] * scales[b];
  }
  sred[bg * 16 + ol] = s;
  __syncthreads();
  if (t < 16) {
    float tot = 0.f;
#pragma unroll
    for (int g = 0; g < 32; ++g) tot += sred[g * 16 + t];
    yv[o0 + t] = tot * inv;
  }
}

// ---- Phase Ctx: 64 blocks, 4 ctx entries each. ctx[i] = Wv[i].yv_h + bv[i] ----
__device__ __forceinline__ void phaseCtx(const float* __restrict__ W, const float* __restrict__ inb,
                                         const float* __restrict__ yv, float* __restrict__ ctx,
                                         int b, int t) {
  const int lane = t & 63, w = t >> 6;
  if (w < 4) {
    const int i = b * 4 + w;
    const int h = i >> 6;
    float4 wv = *(const float4*)&W[(size_t)(512 + i) * 256 + lane * 4];
    float4 yy = *(const float4*)&yv[h * 256 + lane * 4];
    float p = dot4(wv, yy);
#pragma unroll
    for (int m = 1; m < 64; m <<= 1) p += __shfl_xor(p, m);
    if (lane == 0) ctx[i] = p + inb[512 + i];
  }
}

// ---- Phase Out: 16 blocks, 16 outputs each. out[e] = Wout[e].ctx + bout[e] ----
__device__ __forceinline__ void phaseOut(const float* __restrict__ Wout, const float* __restrict__ bout,
                                         const float* __restrict__ ctx, float* __restrict__ out,
                                         int b, int t) {
  const int lane = t & 63, w = t >> 6;
  const float4 cv = *(const float4*)&ctx[lane * 4];
#pragma unroll
  for (int k = 0; k < 2; ++k) {
    const int e = b * 16 + w * 2 + k;
    float4 wv = *(const float4*)&Wout[(size_t)e * 256 + lane * 4];
    float p = dot4(wv, cv);
#pragma unroll
    for (int m = 1; m < 64; m <<= 1) p += __shfl_xor(p, m);
    if (lane == 0) out[e] = p + bout[e];
  }
}

// ---- Single cooperative launch: ONE grid.sync ----
__global__ void __launch_bounds__(512, 1) mha_one(const float* __restrict__ x,
                                                  const float* __restrict__ W,
                                                  const float* __restrict__ inb,
                                                  const float* __restrict__ Wout,
                                                  const float* __restrict__ bout,
                                                  float* __restrict__ out,
                                                  float* __restrict__ ws) {
  __shared__ __align__(16) float sh[8256];
  const int t = threadIdx.x, bid = blockIdx.x;
  const int lane = t & 63, w = t >> 6;
  int* flagA = (int*)(ws + WS_CNT);
  int* flagC = flagA + 16;
  int* flagX = flagC + 64;
  cg::grid_group grid = cg::this_grid();

  const int r0 = bid * 128 + w * 16;
  float4 xvA[8], xvB[8];

  if (bid < 16) {
    phaseA_kq(x, W, inb, ws + WS_KQ, ws + WS_C4, sh, bid, t);
    set_flag(&flagA[bid], t);
#pragma unroll
    for (int r = 0; r < 8; ++r)
      xvA[r] = *(const float4*)&x[(size_t)(r0 + r) * 256 + lane * 4];
#pragma unroll
    for (int r = 0; r < 8; ++r)
      xvB[r] = *(const float4*)&x[(size_t)(r0 + 8 + r) * 256 + lane * 4];
  } else {
#pragma unroll
    for (int r = 0; r < 8; ++r)
      xvA[r] = *(const float4*)&x[(size_t)(r0 + r) * 256 + lane * 4];
#pragma unroll
    for (int r = 0; r < 8; ++r)
      xvB[r] = *(const float4*)&x[(size_t)(r0 + 8 + r) * 256 + lane * 4];
  }

  poll_flags(flagA, 16, t);
  phaseB_core(xvA, xvB, ws + WS_KQ, ws + WS_C4, ws + WS_YP, ws + WS_MP, ws + WS_LP, sh, bid, t);

  grid.sync();  // the single all-to-all rendezvous

  if (bid < 64) {
    phaseC(ws + WS_YP, ws + WS_MP, ws + WS_LP, ws + WS_YV, sh, bid, t);
    set_flag(&flagC[bid], t);
  } else if (bid < 128) {
    poll_flags(flagC, 64, t);
    phaseCtx(W, inb, ws + WS_YV, ws + WS_CTX, bid - 64, t);
    set_flag(&flagX[bid - 64], t);
  } else if (bid < 144) {
    poll_flags(flagX, 64, t);
    phaseOut(Wout, bout, ws + WS_CTX, out, bid - 128, t);
  }
}

// ---- Fallback chain (no coop): 5 launches, stream-ordered, no flags ----
__global__ void __launch_bounds__(512) fb_A(const float* __restrict__ x, const float* __restrict__ W,
                                            const float* __restrict__ inb, float* __restrict__ ws) {
  __shared__ __align__(16) float sh[832];
  phaseA_kq(x, W, inb, ws + WS_KQ, ws + WS_C4, sh, blockIdx.x, threadIdx.x);
}
__global__ void __launch_bounds__(512) fb_B(const float* __restrict__ x, float* __restrict__ ws) {
  __shared__ __align__(16) float sh[8256];
  const int bid = blockIdx.x, t = threadIdx.x;
  const int lane = t & 63, w = t >> 6;
  const int r0 = bid * 128 + w * 16;
  float4 xvA[8], xvB[8];
#pragma unroll
  for (int r = 0; r < 8; ++r)
    xvA[r] = *(const float4*)&x[(size_t)(r0 + r) * 256 + lane * 4];
#pragma unroll
  for (int r = 0; r < 8; ++r)
    xvB[r] = *(const float4*)&x[(size_t)(r0 + 8 + r) * 256 + lane * 4];
  phaseB_core(xvA, xvB, ws + WS_KQ, ws + WS_C4, ws + WS_YP, ws + WS_MP, ws + WS_LP, sh, bid, t);
}
__global__ void __launch_bounds__(512) fb_C(float* __restrict__ ws) {
  __shared__ __align__(16) float sh[1280];
  phaseC(ws + WS_YP, ws + WS_MP, ws + WS_LP, ws + WS_YV, sh, blockIdx.x, threadIdx.x);
}
__global__ void __launch_bounds__(512) fb_X(const float* __restrict__ W, const float* __restrict__ inb,
                                            float* __restrict__ ws) {
  phaseCtx(W, inb, ws + WS_YV, ws + WS_CTX, blockIdx.x, threadIdx.x);
}
__global__ void __launch_bounds__(512) fb_O(const float* __restrict__ Wout, const float* __restrict__ bout,
                                            float* __restrict__ out, float* __restrict__ ws) {
  phaseOut(Wout, bout, ws + WS_CTX, out, blockIdx.x, threadIdx.x);
}

extern "C" void kernel_launch(void* const* d_in, const int* in_sizes, int n_in,
                              void* d_out, int out_size, void* d_ws, size_t ws_size,
                              hipStream_t stream) {
  const float* x = (const float*)d_in[0];
  const float* W = (const float*)d_in[1];
  const float* inb = (const float*)d_in[2];
  const float* Wout = (const float*)d_in[3];
  const float* bout = (const float*)d_in[4];
  float* out = (float*)d_out;
  float* ws = (float*)d_ws;

  // zero flags (A16+C64+X64 = 144 ints)
  hipMemsetAsync((void*)(ws + WS_CNT), 0, 1024, stream);

  int dev = 0;
  (void)hipGetDevice(&dev);
  int coopAttr = 0, ncu = 0, occ = 0;
  bool coop = (hipDeviceGetAttribute(&coopAttr, hipDeviceAttributeCooperativeLaunch, dev) == hipSuccess) &&
              coopAttr != 0;
  coop = coop &&
         (hipDeviceGetAttribute(&ncu, hipDeviceAttributeMultiprocessorCount, dev) == hipSuccess);
  coop = coop &&
         (hipOccupancyMaxActiveBlocksPerMultiprocessor(&occ, mha_one, 512, 0) == hipSuccess);
  coop = coop && (occ * ncu >= NBLK);

  if (coop) {
    void* args[] = {(void*)&x, (void*)&W, (void*)&inb, (void*)&Wout,
                    (void*)&bout, (void*)&out, (void*)&ws};
    if (hipLaunchCooperativeKernel((const void*)mha_one, dim3(NBLK), dim3(512),
                                   args, 0, stream) == hipSuccess)
      return;
  }
  fb_A<<<16, 512, 0, stream>>>(x, W, inb, ws);
  fb_B<<<NBLK, 512, 0, stream>>>(x, ws);
  fb_C<<<64, 512, 0, stream>>>(ws);
  fb_X<<<64, 512, 0, stream>>>(W, inb, ws);
  fb_O<<<16, 512, 0, stream>>>(Wout, bout, out, ws);
}